// Round 12
// baseline (206.500 us; speedup 1.0000x reference)
//
#include <hip/hip_runtime.h>
#include <hip/hip_bf16.h>
#include <math.h>

// GraphSAGE 2-layer, mean aggregation, N=100000, F=500, hid=8, classes=10.
// Project-before-aggregate + bucketed counting-sort CSR (no global atomics)
// + per-dst sorted edge lists + register-accumulating aggregation (no LDS atomics).
// Round 12: MFMA proj1 with COALESCED loads — per-wave LDS staging of the
// contiguous 16-row x-tile (f32->bf16), B fragments preloaded in 64 VGPRs.
// R11 evidence: direct-from-global A fragments were TA-bound (~8-10 cyc per
// distinct 64B line per instr, 32 lines/instr -> ~83us). Staging makes every
// global load a dense 1KB wave access.

#define NBKT_MAX 1600     // max buckets (N <= 102400)
#define P_BLOCKS 256      // partition blocks for hist/scatter
#define BSH 6             // bucket shift: 64 nodes/bucket
#define BSZ 64
#define SEG_CAP 4096      // max edges per bucket segment (mean 2048, sigma 45)
#define PT_ROW 520        // LDS row stride (bf16): 1040B = 16B-aligned, 2-way banks

typedef float f4v __attribute__((ext_vector_type(4)));
typedef float f32x4 __attribute__((ext_vector_type(4)));
typedef unsigned u32x4 __attribute__((ext_vector_type(4)));
typedef __bf16 bf16x8 __attribute__((ext_vector_type(8)));

__device__ __forceinline__ unsigned f2bf(float f) {   // RNE f32->bf16 bits
    unsigned u = __float_as_uint(f);
    return (u + 0x7FFFu + ((u >> 16) & 1u)) >> 16;
}
__device__ __forceinline__ float bflo(unsigned w) { return __uint_as_float(w << 16); }
__device__ __forceinline__ float bfhi(unsigned w) { return __uint_as_float(w & 0xFFFF0000u); }

__device__ __forceinline__ unsigned pk2(float lo, float hi) {  // 2xf32 -> packed bf16x2
    union { __hip_bfloat162 h; unsigned u; } c;
    c.h = __float22bfloat162_rn(make_float2(lo, hi));
    return c.u;
}

// MFMA projection with LDS-staged A tile.
// Each wave owns a [16][520] bf16 LDS slice; per tile: 32 coalesced 1KB global
// loads -> cvt -> ds_write_b64; then 16 x {ds_read_b128 A-frag; MFMA} with the
// 16 B-fragments (W^T) held in registers (loaded once, zero-padded past k=500).
__global__ __launch_bounds__(128) void proj1_kernel(
    const float* __restrict__ x,
    const float* __restrict__ W1l,   // [8,500]
    const float* __restrict__ W1r,   // [8,500]
    unsigned short* __restrict__ yab, // [N,8] bf16 = x@W1l.T (aggregated part)
    float* __restrict__ yr,           // [N,8] f32  = x@W1r.T (self part)
    int N)
{
    __shared__ __align__(16) unsigned short xls[2][16 * PT_ROW];
    const int lane = threadIdx.x & 63;
    const int wv   = threadIdx.x >> 6;
    unsigned short* xw = xls[wv];
    const int m  = lane & 15;        // A row-in-tile / output column
    const int kg = lane >> 4;        // k-group

    // ---- one-time B-fragment preload into registers (fully unrolled) ----
    const float* wrow = (m < 8) ? (W1l + m * 500) : (W1r + (m - 8) * 500);
    const f4v zero4 = {0.f, 0.f, 0.f, 0.f};
    u32x4 bq[16];
    #pragma unroll
    for (int s = 0; s < 16; ++s) {
        int k0 = s * 32 + kg * 8;
        f4v wa = (k0 + 4 <= 500) ? *reinterpret_cast<const f4v*>(wrow + k0) : zero4;
        f4v wb = (k0 + 8 <= 500) ? *reinterpret_cast<const f4v*>(wrow + k0 + 4) : zero4;
        bq[s].x = pk2(wa.x, wa.y);
        bq[s].y = pk2(wa.z, wa.w);
        bq[s].z = pk2(wb.x, wb.y);
        bq[s].w = pk2(wb.z, wb.w);
    }

    const int nt = (N + 15) >> 4;
    const int gw = blockIdx.x * 2 + wv;
    const int nw = gridDim.x * 2;
    const size_t xcap = (size_t)N * 500;

    for (int t = gw; t < nt; t += nw) {
        const size_t base = (size_t)t * 16 * 500;   // f32 index of tile start (16B-aligned)

        // ---- stage 16 rows -> bf16 LDS (coalesced 1KB loads) ----
        #pragma unroll 4
        for (int r = 0; r < 16; ++r) {
            const float* xr = x + base + (size_t)r * 500;
            uint2* lr = reinterpret_cast<uint2*>(xw + r * PT_ROW);  // 8B slots = f4v slots
            {   // f32 0..255
                size_t gi = base + (size_t)r * 500 + (size_t)lane * 4;
                f4v v = (gi + 4 <= xcap) ? *reinterpret_cast<const f4v*>(xr + lane * 4) : zero4;
                lr[lane] = make_uint2(pk2(v.x, v.y), pk2(v.z, v.w));
            }
            {   // f32 256..499 (lanes 0..60); lanes 61..63 zero the pad (f32 500..511)
                int i4 = 64 + lane;
                if (lane < 61) {
                    size_t gi = base + (size_t)r * 500 + (size_t)i4 * 4;
                    f4v v = (gi + 4 <= xcap) ? *reinterpret_cast<const f4v*>(xr + i4 * 4) : zero4;
                    lr[i4] = make_uint2(pk2(v.x, v.y), pk2(v.z, v.w));
                } else {
                    lr[i4] = make_uint2(0u, 0u);   // i4 = 125..127 -> elements 500..511
                }
            }
        }
        // wave-private slice: no barrier needed; compiler orders LDS writes->reads.

        // ---- 16 MFMA steps ----
        f32x4 acc = {0.f, 0.f, 0.f, 0.f};
        const unsigned short* ar = xw + m * PT_ROW + kg * 8;
        #pragma unroll
        for (int s = 0; s < 16; ++s) {
            union { u32x4 u; bf16x8 b; } av, bv;
            av.b = *reinterpret_cast<const bf16x8*>(ar + s * 32);
            bv.u = bq[s];
            acc = __builtin_amdgcn_mfma_f32_16x16x32_bf16(av.b, bv.b, acc, 0, 0, 0);
        }

        // C layout (verified R11): col = m, row-in-tile = kg*4 + reg.
        const int ndb = t * 16 + kg * 4;
        #pragma unroll
        for (int r = 0; r < 4; ++r) {
            int nd = ndb + r;
            if (nd < N) {
                float v = acc[r];
                if (m < 8) yab[(size_t)nd * 8 + m] = (unsigned short)f2bf(v);
                else       yr[(size_t)nd * 8 + (m - 8)] = v;
            }
        }
    }
}

// Per-block LDS histogram over dst buckets (bucket = dst>>BSH).
__global__ __launch_bounds__(512) void hist_kernel(
    const int* __restrict__ ei, int E, int chunk, int B,
    int* __restrict__ hist_g)            // [B][P_BLOCKS]
{
    __shared__ int h[NBKT_MAX];
    for (int i = threadIdx.x; i < B; i += 512) h[i] = 0;
    __syncthreads();
    const int p = blockIdx.x;
    const int e0 = p * chunk, e1 = min(e0 + chunk, E);
    int e = e0 + threadIdx.x;
    for (; e + 512 < e1; e += 1024) {
        int d0 = ei[E + e], d1 = ei[E + e + 512];
        atomicAdd(&h[d0 >> BSH], 1);
        atomicAdd(&h[d1 >> BSH], 1);
    }
    for (; e < e1; e += 512) atomicAdd(&h[ei[E + e] >> BSH], 1);
    __syncthreads();
    for (int b = threadIdx.x; b < B; b += 512)
        hist_g[(size_t)b * P_BLOCKS + p] = h[b];
}

// tot[b] = sum_p hist[b][p]
__global__ __launch_bounds__(256) void bsum_kernel(
    const int* __restrict__ hist_g, int* __restrict__ tot)
{
    __shared__ int s[256];
    const int b = blockIdx.x;
    s[threadIdx.x] = hist_g[(size_t)b * P_BLOCKS + threadIdx.x];
    __syncthreads();
    for (int o = 128; o > 0; o >>= 1) {
        if (threadIdx.x < o) s[threadIdx.x] += s[threadIdx.x + o];
        __syncthreads();
    }
    if (threadIdx.x == 0) tot[b] = s[0];
}

// In-place: hist_g[b][p] <- bstart[b] + exclusive_scan_p(hist[b][p]).
__global__ __launch_bounds__(256) void base_kernel(
    int* __restrict__ hist_g, const int* __restrict__ tot, int B,
    int* __restrict__ bstart)
{
    __shared__ int sr[256];
    __shared__ int s2[256];
    __shared__ int bs_sh;
    const int b = blockIdx.x, tid = threadIdx.x;

    int part = 0;
    for (int i = tid; i < b; i += 256) part += tot[i];
    sr[tid] = part;
    __syncthreads();
    for (int o = 128; o > 0; o >>= 1) {
        if (tid < o) sr[tid] += sr[tid + o];
        __syncthreads();
    }
    if (tid == 0) bs_sh = sr[0];
    __syncthreads();
    const int bs = bs_sh;

    const int v = hist_g[(size_t)b * P_BLOCKS + tid];
    s2[tid] = v;
    __syncthreads();
    for (int o = 1; o < 256; o <<= 1) {
        int t = (tid >= o) ? s2[tid - o] : 0;
        __syncthreads();
        s2[tid] += t;
        __syncthreads();
    }
    hist_g[(size_t)b * P_BLOCKS + tid] = bs + s2[tid] - v;   // exclusive base
    if (tid == 0) bstart[b] = bs;
    if (b == B - 1 && tid == 255) bstart[B] = bs + s2[255];
}

// Scatter packed (src | dstLow<<17) into bucket-partitioned csr using LDS cursors.
__global__ __launch_bounds__(512) void scatter2_kernel(
    const int* __restrict__ ei, int E, int chunk, int B,
    const int* __restrict__ base, unsigned* __restrict__ csr)
{
    __shared__ int cur[NBKT_MAX];
    const int p = blockIdx.x;
    for (int b = threadIdx.x; b < B; b += 512) cur[b] = base[(size_t)b * P_BLOCKS + p];
    __syncthreads();
    const int e0 = p * chunk, e1 = min(e0 + chunk, E);
    int e = e0 + threadIdx.x;
    for (; e + 512 < e1; e += 1024) {
        int s0 = ei[e],     s1 = ei[e + 512];
        int d0 = ei[E + e], d1 = ei[E + e + 512];
        int p0 = atomicAdd(&cur[d0 >> BSH], 1);
        int p1 = atomicAdd(&cur[d1 >> BSH], 1);
        csr[p0] = (unsigned)s0 | ((unsigned)(d0 & (BSZ - 1)) << 17);
        csr[p1] = (unsigned)s1 | ((unsigned)(d1 & (BSZ - 1)) << 17);
    }
    for (; e < e1; e += 512) {
        int s0 = ei[e], d0 = ei[E + e];
        int p0 = atomicAdd(&cur[d0 >> BSH], 1);
        csr[p0] = (unsigned)s0 | ((unsigned)(d0 & (BSZ - 1)) << 17);
    }
}

// Per-bucket counting sort by dst node (in-place via LDS staging).
__global__ __launch_bounds__(256) void sortB_kernel(
    const int* __restrict__ bstart,
    unsigned* __restrict__ csr,
    int* __restrict__ nodeoff,       // [B*64+1]
    int B)
{
    __shared__ unsigned stage[SEG_CAP];
    __shared__ int cnt[BSZ];
    __shared__ int cur[BSZ];
    const int b = blockIdx.x, tid = threadIdx.x;
    const int e0 = bstart[b], e1 = bstart[b + 1];
    const int n = e1 - e0;

    if (tid < BSZ) cnt[tid] = 0;
    for (int i = tid; i < n; i += 256) stage[i] = csr[e0 + i];
    __syncthreads();
    for (int i = tid; i < n; i += 256) atomicAdd(&cnt[stage[i] >> 17], 1);
    __syncthreads();
    if (tid < BSZ) {
        int v = cnt[tid];
        int incl = v;
        #pragma unroll
        for (int o = 1; o < 64; o <<= 1) {
            int t = __shfl_up(incl, o);
            if ((tid & 63) >= o) incl += t;
        }
        int excl = e0 + incl - v;
        cur[tid] = excl;
        nodeoff[(size_t)b * BSZ + tid] = excl;
        if (b == B - 1 && tid == 0) nodeoff[(size_t)B * BSZ] = e1;
    }
    __syncthreads();
    for (int i = tid; i < n; i += 256) {
        unsigned pk = stage[i];
        int pos = atomicAdd(&cur[pk >> 17], 1);
        csr[pos] = pk & 0x1FFFFu;
    }
}

// Layer-1 aggregation, atomic-free: 4 lanes per node stride its contiguous
// edge list, accumulate 8 f32 in registers, shfl-combine, lane-0 epilogue.
__global__ __launch_bounds__(256) void agg1R_kernel(
    const int* __restrict__ nodeoff,
    const unsigned* __restrict__ csr,     // sorted src indices
    const unsigned short* __restrict__ yab, // [N,8] bf16
    const float* __restrict__ yr,    // [N,8] f32
    const float* __restrict__ b1,    // [8]
    const float* __restrict__ W2l,   // [10,8]
    const float* __restrict__ b2,    // [10]
    const float* __restrict__ W2r,   // [10,8]
    unsigned short* __restrict__ zlb, // [N,16] bf16 rows (32B)
    float* __restrict__ zrb,         // [N,12]  (col10 = invdeg)
    int N)
{
    __shared__ float wb[178];        // b1[8] | W2l[80] | b2[10] | W2r[80]
    const int tid = threadIdx.x;
    if (tid < 178)
        wb[tid] = (tid < 8) ? b1[tid] : (tid < 88) ? W2l[tid - 8]
                 : (tid < 98) ? b2[tid - 88] : W2r[tid - 98];
    __syncthreads();

    const int g = tid >> 2;          // node slot 0..63
    const int q = tid & 3;
    const int node = blockIdx.x * BSZ + g;
    const int gs = nodeoff[node], ge = nodeoff[node + 1];
    const uint4* ya4 = reinterpret_cast<const uint4*>(yab);

    float a[8];
    #pragma unroll
    for (int i = 0; i < 8; ++i) a[i] = 0.f;

    for (int e = gs + q; e < ge; e += 4) {
        unsigned s = csr[e];
        uint4 r = ya4[s];
        a[0] += bflo(r.x); a[1] += bfhi(r.x);
        a[2] += bflo(r.y); a[3] += bfhi(r.y);
        a[4] += bflo(r.z); a[5] += bfhi(r.z);
        a[6] += bflo(r.w); a[7] += bfhi(r.w);
    }
    #pragma unroll
    for (int i = 0; i < 8; ++i) {
        a[i] += __shfl_xor(a[i], 1);
        a[i] += __shfl_xor(a[i], 2);
    }

    if (q != 0 || node >= N) return;
    const int deg = ge - gs;
    const float inv = 1.f / fmaxf((float)deg, 1.f);
    const f4v* yr4 = reinterpret_cast<const f4v*>(yr + (size_t)node * 8);
    f4v r0 = yr4[0], r1 = yr4[1];
    const float rr[8] = {r0.x, r0.y, r0.z, r0.w, r1.x, r1.y, r1.z, r1.w};

    float h[8];
    #pragma unroll
    for (int t = 0; t < 8; ++t) {
        float v = a[t] * inv + wb[t] + rr[t];
        h[t] = v > 0.f ? v : expm1f(v);   // ELU(alpha=1)
    }

    float zlv[10], zrv[10];
    #pragma unroll
    for (int k = 0; k < 10; ++k) {
        float al = 0.f, ar = wb[88 + k];
        #pragma unroll
        for (int t = 0; t < 8; ++t) {
            al += wb[8 + k * 8 + t]  * h[t];
            ar += wb[98 + k * 8 + t] * h[t];
        }
        zlv[k] = al; zrv[k] = ar;
    }

    uint4 h0, h1;
    h0.x = f2bf(zlv[0]) | (f2bf(zlv[1]) << 16);
    h0.y = f2bf(zlv[2]) | (f2bf(zlv[3]) << 16);
    h0.z = f2bf(zlv[4]);
    h0.w = 0u;
    h1.x = f2bf(zlv[5]) | (f2bf(zlv[6]) << 16);
    h1.y = f2bf(zlv[7]) | (f2bf(zlv[8]) << 16);
    h1.z = f2bf(zlv[9]);
    h1.w = 0u;
    uint4* zl4w = reinterpret_cast<uint4*>(zlb + (size_t)node * 16);
    zl4w[0] = h0;
    zl4w[1] = h1;

    float4* zr4w = reinterpret_cast<float4*>(zrb + (size_t)node * 12);
    zr4w[0] = make_float4(zrv[0], zrv[1], zrv[2], zrv[3]);
    zr4w[1] = make_float4(zrv[4], zrv[5], zrv[6], zrv[7]);
    zr4w[2] = make_float4(zrv[8], zrv[9], inv, 0.f);   // col10 = invdeg
}

// Layer-2 aggregation, atomic-free: 4 lanes per node, register accumulate
// 10 f32, shfl-combine, lane-0 does mean + r-branch + log-softmax.
__global__ __launch_bounds__(256) void agg2R_kernel(
    const int* __restrict__ nodeoff,
    const unsigned* __restrict__ csr,     // sorted src indices
    const unsigned short* __restrict__ zlb, // [N,16] bf16
    const float* __restrict__ zrb,   // [N,12] (col10 = invdeg)
    float* __restrict__ out,         // [N,10]
    int N)
{
    const int tid = threadIdx.x;
    const int g = tid >> 2;
    const int q = tid & 3;
    const int node = blockIdx.x * BSZ + g;
    const int gs = nodeoff[node], ge = nodeoff[node + 1];
    const uint4* zl4 = reinterpret_cast<const uint4*>(zlb);

    float a[10];
    #pragma unroll
    for (int i = 0; i < 10; ++i) a[i] = 0.f;

    for (int e = gs + q; e < ge; e += 4) {
        unsigned s = csr[e];
        uint4 rA = zl4[(size_t)s * 2];
        uint4 rB = zl4[(size_t)s * 2 + 1];
        a[0] += bflo(rA.x); a[1] += bfhi(rA.x);
        a[2] += bflo(rA.y); a[3] += bfhi(rA.y);
        a[4] += bflo(rA.z);
        a[5] += bflo(rB.x); a[6] += bfhi(rB.x);
        a[7] += bflo(rB.y); a[8] += bfhi(rB.y);
        a[9] += bflo(rB.z);
    }
    #pragma unroll
    for (int i = 0; i < 10; ++i) {
        a[i] += __shfl_xor(a[i], 1);
        a[i] += __shfl_xor(a[i], 2);
    }

    if (q != 0 || node >= N) return;
    const float* zr = zrb + (size_t)node * 12;
    const float inv = zr[10];
    float v[10];
    float mx = -1e30f;
    #pragma unroll
    for (int k = 0; k < 10; ++k) {
        v[k] = a[k] * inv + zr[k];
        mx = fmaxf(mx, v[k]);
    }
    float ssum = 0.f;
    #pragma unroll
    for (int k = 0; k < 10; ++k) ssum += expf(v[k] - mx);
    const float lse = mx + logf(ssum);
    float2* o = reinterpret_cast<float2*>(out + (size_t)node * 10);
    o[0] = make_float2(v[0] - lse, v[1] - lse);
    o[1] = make_float2(v[2] - lse, v[3] - lse);
    o[2] = make_float2(v[4] - lse, v[5] - lse);
    o[3] = make_float2(v[6] - lse, v[7] - lse);
    o[4] = make_float2(v[8] - lse, v[9] - lse);
}

extern "C" void kernel_launch(void* const* d_in, const int* in_sizes, int n_in,
                              void* d_out, int out_size, void* d_ws, size_t ws_size,
                              hipStream_t stream) {
    const float* x   = (const float*)d_in[0];
    const int*   ei  = (const int*)d_in[1];
    const float* W1l = (const float*)d_in[2];
    const float* b1l = (const float*)d_in[3];
    const float* W1r = (const float*)d_in[4];
    const float* W2l = (const float*)d_in[5];
    const float* b2l = (const float*)d_in[6];
    const float* W2r = (const float*)d_in[7];
    float* out = (float*)d_out;

    const int N = in_sizes[0] / 500;
    const int E = in_sizes[1] / 2;
    const int B = (N + BSZ - 1) >> BSH;       // buckets of BSZ nodes
    const int chunk = (E + P_BLOCKS - 1) / P_BLOCKS;

    // workspace: ints first, then 16B-aligned arrays (~33 MB)
    int* hist_g  = (int*)d_ws;                       // [B*P_BLOCKS] (hist, then base in-place)
    int* tot     = hist_g + (size_t)B * P_BLOCKS;    // [B]
    int* bstart  = tot + B;                          // [B+1]
    int* nodeoff = bstart + (B + 1);                 // [B*64+1]
    unsigned* csr = (unsigned*)(nodeoff + (size_t)B * BSZ + 1); // [E]
    size_t off = ((char*)(csr + E) - (char*)d_ws + 15) & ~(size_t)15;
    unsigned short* yab = (unsigned short*)((char*)d_ws + off);  // [N,8] bf16
    off = (off + (size_t)N * 16 + 15) & ~(size_t)15;
    unsigned short* zlb = (unsigned short*)((char*)d_ws + off);  // [N,16] bf16
    off = (off + (size_t)N * 32 + 15) & ~(size_t)15;
    float* yr  = (float*)((char*)d_ws + off);                    // [N,8] f32
    float* zrb = yr + (size_t)8 * N;                             // [N,12] f32

    proj1_kernel<<<1024, 128, 0, stream>>>(x, W1l, W1r, yab, yr, N);
    hist_kernel<<<P_BLOCKS, 512, 0, stream>>>(ei, E, chunk, B, hist_g);
    bsum_kernel<<<B, 256, 0, stream>>>(hist_g, tot);
    base_kernel<<<B, 256, 0, stream>>>(hist_g, tot, B, bstart);
    scatter2_kernel<<<P_BLOCKS, 512, 0, stream>>>(ei, E, chunk, B, hist_g, csr);
    sortB_kernel<<<B, 256, 0, stream>>>(bstart, csr, nodeoff, B);
    agg1R_kernel<<<B, 256, 0, stream>>>(nodeoff, csr, yab, yr, b1l, W2l, b2l, W2r,
                                        zlb, zrb, N);
    agg2R_kernel<<<B, 256, 0, stream>>>(nodeoff, csr, zlb, zrb, out, N);
}

// Round 13
// 176.235 us; speedup vs baseline: 1.1717x; 1.1717x over previous
//
#include <hip/hip_runtime.h>
#include <hip/hip_bf16.h>
#include <math.h>

// GraphSAGE 2-layer, mean aggregation, N=100000, F=500, hid=8, classes=10.
// Project-before-aggregate + bucketed counting-sort CSR (no global atomics)
// + per-dst sorted edge lists + register-accumulating aggregation (no LDS atomics).
// Round 13: proj1 = R10 coalesced+prefetch structure, but W held in REGISTERS
// (128 VGPR, loaded once per wave) instead of LDS. R10 was LDS-pipe bound
// (~756 cyc/pair: 32 ds_read_b128 of W + 62 shuffles); this deletes the W reads.
// MFMA variants (R11 direct: TA-divergent; R12 staged: latency-serial) both lost.

#define NBKT_MAX 1600     // max buckets (N <= 102400)
#define P_BLOCKS 256      // partition blocks for hist/scatter
#define BSH 6             // bucket shift: 64 nodes/bucket
#define BSZ 64
#define SEG_CAP 4096      // max edges per bucket segment (mean 2048, sigma 45)

typedef float f4v __attribute__((ext_vector_type(4)));

__device__ __forceinline__ float dot4(f4v a, f4v b) {
    return a.x * b.x + a.y * b.y + a.z * b.z + a.w * b.w;
}
__device__ __forceinline__ unsigned f2bf(float f) {   // RNE f32->bf16 bits
    unsigned u = __float_as_uint(f);
    return (u + 0x7FFFu + ((u >> 16) & 1u)) >> 16;
}
__device__ __forceinline__ float bflo(unsigned w) { return __uint_as_float(w << 16); }
__device__ __forceinline__ float bfhi(unsigned w) { return __uint_as_float(w & 0xFFFF0000u); }

// Coalesced projection, software-pipelined, W-in-registers.
// Each wave handles 2 nodes/iter; lanes read x rows contiguously; each lane
// holds its k-slice of all 16 W rows in 32 f4v registers (one-time load).
__global__ __launch_bounds__(256) void proj1_kernel(
    const float* __restrict__ x,
    const float* __restrict__ W1l,   // [8,500]
    const float* __restrict__ W1r,   // [8,500]
    unsigned short* __restrict__ yab, // [N,8] bf16 = x@W1l.T (aggregated part)
    float* __restrict__ yr,           // [N,8] f32  = x@W1r.T (self part)
    int N)
{
    const int lane = threadIdx.x & 63;
    const int wv   = threadIdx.x >> 6;
    const f4v zero = {0.f, 0.f, 0.f, 0.f};

    // One-time: this lane's k-slices of all 16 W rows (k = lane*4.. and 256+lane*4..)
    f4v wA[16], wB[16];
    #pragma unroll
    for (int m = 0; m < 16; ++m) {
        const float* wr = (m < 8) ? (W1l + m * 500) : (W1r + (m - 8) * 500);
        wA[m] = *reinterpret_cast<const f4v*>(wr + lane * 4);
        wB[m] = (lane < 61) ? *reinterpret_cast<const f4v*>(wr + 256 + lane * 4) : zero;
    }

    const int P = (N + 1) >> 1;                 // node pairs
    const int gw = blockIdx.x * 4 + wv;
    const int nw = gridDim.x * 4;

    int p = gw;
    f4v a0 = zero, a1 = zero, b0 = zero, b1 = zero;
    if (p < P) {
        const int n0 = p * 2;
        const int n1 = min(n0 + 1, N - 1);
        const f4v* xr0 = reinterpret_cast<const f4v*>(x + (size_t)n0 * 500);
        const f4v* xr1 = reinterpret_cast<const f4v*>(x + (size_t)n1 * 500);
        a0 = xr0[lane];
        a1 = xr1[lane];
        b0 = (lane < 61) ? xr0[64 + lane] : zero;
        b1 = (lane < 61) ? xr1[64 + lane] : zero;
    }

    while (p < P) {
        const int pn = p + nw;
        f4v na0 = zero, na1 = zero, nb0 = zero, nb1 = zero;
        if (pn < P) {                       // issue next pair's loads NOW
            const int m0 = pn * 2;
            const int m1 = min(m0 + 1, N - 1);
            const f4v* q0 = reinterpret_cast<const f4v*>(x + (size_t)m0 * 500);
            const f4v* q1 = reinterpret_cast<const f4v*>(x + (size_t)m1 * 500);
            na0 = q0[lane];
            na1 = q1[lane];
            nb0 = (lane < 61) ? q0[64 + lane] : zero;
            nb1 = (lane < 61) ? q1[64 + lane] : zero;
        }

        float acc[32];
        #pragma unroll
        for (int i = 0; i < 32; ++i) acc[i] = 0.f;

        #pragma unroll
        for (int m = 0; m < 16; ++m) {
            acc[m]      += dot4(a0, wA[m]) + dot4(b0, wB[m]);
            acc[16 + m] += dot4(a1, wA[m]) + dot4(b1, wB[m]);
        }

        // bisection reduce: 32 values over 64 lanes
        #pragma unroll
        for (int i = 0; i < 16; ++i) {
            float keep = (lane & 1) ? acc[i + 16] : acc[i];
            float send = (lane & 1) ? acc[i]      : acc[i + 16];
            acc[i] = keep + __shfl_xor(send, 1);
        }
        #pragma unroll
        for (int i = 0; i < 8; ++i) {
            float keep = (lane & 2) ? acc[i + 8] : acc[i];
            float send = (lane & 2) ? acc[i]     : acc[i + 8];
            acc[i] = keep + __shfl_xor(send, 2);
        }
        #pragma unroll
        for (int i = 0; i < 4; ++i) {
            float keep = (lane & 4) ? acc[i + 4] : acc[i];
            float send = (lane & 4) ? acc[i]     : acc[i + 4];
            acc[i] = keep + __shfl_xor(send, 4);
        }
        #pragma unroll
        for (int i = 0; i < 2; ++i) {
            float keep = (lane & 8) ? acc[i + 2] : acc[i];
            float send = (lane & 8) ? acc[i]     : acc[i + 2];
            acc[i] = keep + __shfl_xor(send, 8);
        }
        {
            float keep = (lane & 16) ? acc[1] : acc[0];
            float send = (lane & 16) ? acc[0] : acc[1];
            acc[0] = keep + __shfl_xor(send, 16);
        }
        float tot = acc[0] + __shfl_xor(acc[0], 32);

        if (lane < 32) {
            int idx = ((lane & 1) << 4) | ((lane & 2) << 2) | (lane & 4)
                    | ((lane & 8) >> 2) | ((lane & 16) >> 4);
            int node = p * 2 + (idx >> 4);
            int m = idx & 15;
            if (node < N) {
                if (m < 8) yab[(size_t)node * 8 + m] = (unsigned short)f2bf(tot);
                else       yr[(size_t)node * 8 + m - 8] = tot;
            }
        }

        a0 = na0; a1 = na1; b0 = nb0; b1 = nb1;
        p = pn;
    }
}

// Per-block LDS histogram over dst buckets (bucket = dst>>BSH).
__global__ __launch_bounds__(512) void hist_kernel(
    const int* __restrict__ ei, int E, int chunk, int B,
    int* __restrict__ hist_g)            // [B][P_BLOCKS]
{
    __shared__ int h[NBKT_MAX];
    for (int i = threadIdx.x; i < B; i += 512) h[i] = 0;
    __syncthreads();
    const int p = blockIdx.x;
    const int e0 = p * chunk, e1 = min(e0 + chunk, E);
    int e = e0 + threadIdx.x;
    for (; e + 512 < e1; e += 1024) {
        int d0 = ei[E + e], d1 = ei[E + e + 512];
        atomicAdd(&h[d0 >> BSH], 1);
        atomicAdd(&h[d1 >> BSH], 1);
    }
    for (; e < e1; e += 512) atomicAdd(&h[ei[E + e] >> BSH], 1);
    __syncthreads();
    for (int b = threadIdx.x; b < B; b += 512)
        hist_g[(size_t)b * P_BLOCKS + p] = h[b];
}

// tot[b] = sum_p hist[b][p]
__global__ __launch_bounds__(256) void bsum_kernel(
    const int* __restrict__ hist_g, int* __restrict__ tot)
{
    __shared__ int s[256];
    const int b = blockIdx.x;
    s[threadIdx.x] = hist_g[(size_t)b * P_BLOCKS + threadIdx.x];
    __syncthreads();
    for (int o = 128; o > 0; o >>= 1) {
        if (threadIdx.x < o) s[threadIdx.x] += s[threadIdx.x + o];
        __syncthreads();
    }
    if (threadIdx.x == 0) tot[b] = s[0];
}

// In-place: hist_g[b][p] <- bstart[b] + exclusive_scan_p(hist[b][p]).
__global__ __launch_bounds__(256) void base_kernel(
    int* __restrict__ hist_g, const int* __restrict__ tot, int B,
    int* __restrict__ bstart)
{
    __shared__ int sr[256];
    __shared__ int s2[256];
    __shared__ int bs_sh;
    const int b = blockIdx.x, tid = threadIdx.x;

    int part = 0;
    for (int i = tid; i < b; i += 256) part += tot[i];
    sr[tid] = part;
    __syncthreads();
    for (int o = 128; o > 0; o >>= 1) {
        if (tid < o) sr[tid] += sr[tid + o];
        __syncthreads();
    }
    if (tid == 0) bs_sh = sr[0];
    __syncthreads();
    const int bs = bs_sh;

    const int v = hist_g[(size_t)b * P_BLOCKS + tid];
    s2[tid] = v;
    __syncthreads();
    for (int o = 1; o < 256; o <<= 1) {
        int t = (tid >= o) ? s2[tid - o] : 0;
        __syncthreads();
        s2[tid] += t;
        __syncthreads();
    }
    hist_g[(size_t)b * P_BLOCKS + tid] = bs + s2[tid] - v;   // exclusive base
    if (tid == 0) bstart[b] = bs;
    if (b == B - 1 && tid == 255) bstart[B] = bs + s2[255];
}

// Scatter packed (src | dstLow<<17) into bucket-partitioned csr using LDS cursors.
__global__ __launch_bounds__(512) void scatter2_kernel(
    const int* __restrict__ ei, int E, int chunk, int B,
    const int* __restrict__ base, unsigned* __restrict__ csr)
{
    __shared__ int cur[NBKT_MAX];
    const int p = blockIdx.x;
    for (int b = threadIdx.x; b < B; b += 512) cur[b] = base[(size_t)b * P_BLOCKS + p];
    __syncthreads();
    const int e0 = p * chunk, e1 = min(e0 + chunk, E);
    int e = e0 + threadIdx.x;
    for (; e + 512 < e1; e += 1024) {
        int s0 = ei[e],     s1 = ei[e + 512];
        int d0 = ei[E + e], d1 = ei[E + e + 512];
        int p0 = atomicAdd(&cur[d0 >> BSH], 1);
        int p1 = atomicAdd(&cur[d1 >> BSH], 1);
        csr[p0] = (unsigned)s0 | ((unsigned)(d0 & (BSZ - 1)) << 17);
        csr[p1] = (unsigned)s1 | ((unsigned)(d1 & (BSZ - 1)) << 17);
    }
    for (; e < e1; e += 512) {
        int s0 = ei[e], d0 = ei[E + e];
        int p0 = atomicAdd(&cur[d0 >> BSH], 1);
        csr[p0] = (unsigned)s0 | ((unsigned)(d0 & (BSZ - 1)) << 17);
    }
}

// Per-bucket counting sort by dst node (in-place via LDS staging).
__global__ __launch_bounds__(256) void sortB_kernel(
    const int* __restrict__ bstart,
    unsigned* __restrict__ csr,
    int* __restrict__ nodeoff,       // [B*64+1]
    int B)
{
    __shared__ unsigned stage[SEG_CAP];
    __shared__ int cnt[BSZ];
    __shared__ int cur[BSZ];
    const int b = blockIdx.x, tid = threadIdx.x;
    const int e0 = bstart[b], e1 = bstart[b + 1];
    const int n = e1 - e0;

    if (tid < BSZ) cnt[tid] = 0;
    for (int i = tid; i < n; i += 256) stage[i] = csr[e0 + i];
    __syncthreads();
    for (int i = tid; i < n; i += 256) atomicAdd(&cnt[stage[i] >> 17], 1);
    __syncthreads();
    if (tid < BSZ) {
        int v = cnt[tid];
        int incl = v;
        #pragma unroll
        for (int o = 1; o < 64; o <<= 1) {
            int t = __shfl_up(incl, o);
            if ((tid & 63) >= o) incl += t;
        }
        int excl = e0 + incl - v;
        cur[tid] = excl;
        nodeoff[(size_t)b * BSZ + tid] = excl;
        if (b == B - 1 && tid == 0) nodeoff[(size_t)B * BSZ] = e1;
    }
    __syncthreads();
    for (int i = tid; i < n; i += 256) {
        unsigned pk = stage[i];
        int pos = atomicAdd(&cur[pk >> 17], 1);
        csr[pos] = pk & 0x1FFFFu;
    }
}

// Layer-1 aggregation, atomic-free: 4 lanes per node stride its contiguous
// edge list, accumulate 8 f32 in registers, shfl-combine, lane-0 epilogue.
__global__ __launch_bounds__(256) void agg1R_kernel(
    const int* __restrict__ nodeoff,
    const unsigned* __restrict__ csr,     // sorted src indices
    const unsigned short* __restrict__ yab, // [N,8] bf16
    const float* __restrict__ yr,    // [N,8] f32
    const float* __restrict__ b1,    // [8]
    const float* __restrict__ W2l,   // [10,8]
    const float* __restrict__ b2,    // [10]
    const float* __restrict__ W2r,   // [10,8]
    unsigned short* __restrict__ zlb, // [N,16] bf16 rows (32B)
    float* __restrict__ zrb,         // [N,12]  (col10 = invdeg)
    int N)
{
    __shared__ float wb[178];        // b1[8] | W2l[80] | b2[10] | W2r[80]
    const int tid = threadIdx.x;
    if (tid < 178)
        wb[tid] = (tid < 8) ? b1[tid] : (tid < 88) ? W2l[tid - 8]
                 : (tid < 98) ? b2[tid - 88] : W2r[tid - 98];
    __syncthreads();

    const int g = tid >> 2;          // node slot 0..63
    const int q = tid & 3;
    const int node = blockIdx.x * BSZ + g;
    const int gs = nodeoff[node], ge = nodeoff[node + 1];
    const uint4* ya4 = reinterpret_cast<const uint4*>(yab);

    float a[8];
    #pragma unroll
    for (int i = 0; i < 8; ++i) a[i] = 0.f;

    for (int e = gs + q; e < ge; e += 4) {
        unsigned s = csr[e];
        uint4 r = ya4[s];
        a[0] += bflo(r.x); a[1] += bfhi(r.x);
        a[2] += bflo(r.y); a[3] += bfhi(r.y);
        a[4] += bflo(r.z); a[5] += bfhi(r.z);
        a[6] += bflo(r.w); a[7] += bfhi(r.w);
    }
    #pragma unroll
    for (int i = 0; i < 8; ++i) {
        a[i] += __shfl_xor(a[i], 1);
        a[i] += __shfl_xor(a[i], 2);
    }

    if (q != 0 || node >= N) return;
    const int deg = ge - gs;
    const float inv = 1.f / fmaxf((float)deg, 1.f);
    const f4v* yr4 = reinterpret_cast<const f4v*>(yr + (size_t)node * 8);
    f4v r0 = yr4[0], r1 = yr4[1];
    const float rr[8] = {r0.x, r0.y, r0.z, r0.w, r1.x, r1.y, r1.z, r1.w};

    float h[8];
    #pragma unroll
    for (int t = 0; t < 8; ++t) {
        float v = a[t] * inv + wb[t] + rr[t];
        h[t] = v > 0.f ? v : expm1f(v);   // ELU(alpha=1)
    }

    float zlv[10], zrv[10];
    #pragma unroll
    for (int k = 0; k < 10; ++k) {
        float al = 0.f, ar = wb[88 + k];
        #pragma unroll
        for (int t = 0; t < 8; ++t) {
            al += wb[8 + k * 8 + t]  * h[t];
            ar += wb[98 + k * 8 + t] * h[t];
        }
        zlv[k] = al; zrv[k] = ar;
    }

    uint4 h0, h1;
    h0.x = f2bf(zlv[0]) | (f2bf(zlv[1]) << 16);
    h0.y = f2bf(zlv[2]) | (f2bf(zlv[3]) << 16);
    h0.z = f2bf(zlv[4]);
    h0.w = 0u;
    h1.x = f2bf(zlv[5]) | (f2bf(zlv[6]) << 16);
    h1.y = f2bf(zlv[7]) | (f2bf(zlv[8]) << 16);
    h1.z = f2bf(zlv[9]);
    h1.w = 0u;
    uint4* zl4w = reinterpret_cast<uint4*>(zlb + (size_t)node * 16);
    zl4w[0] = h0;
    zl4w[1] = h1;

    float4* zr4w = reinterpret_cast<float4*>(zrb + (size_t)node * 12);
    zr4w[0] = make_float4(zrv[0], zrv[1], zrv[2], zrv[3]);
    zr4w[1] = make_float4(zrv[4], zrv[5], zrv[6], zrv[7]);
    zr4w[2] = make_float4(zrv[8], zrv[9], inv, 0.f);   // col10 = invdeg
}

// Layer-2 aggregation, atomic-free: 4 lanes per node, register accumulate
// 10 f32, shfl-combine, lane-0 does mean + r-branch + log-softmax.
__global__ __launch_bounds__(256) void agg2R_kernel(
    const int* __restrict__ nodeoff,
    const unsigned* __restrict__ csr,     // sorted src indices
    const unsigned short* __restrict__ zlb, // [N,16] bf16
    const float* __restrict__ zrb,   // [N,12] (col10 = invdeg)
    float* __restrict__ out,         // [N,10]
    int N)
{
    const int tid = threadIdx.x;
    const int g = tid >> 2;
    const int q = tid & 3;
    const int node = blockIdx.x * BSZ + g;
    const int gs = nodeoff[node], ge = nodeoff[node + 1];
    const uint4* zl4 = reinterpret_cast<const uint4*>(zlb);

    float a[10];
    #pragma unroll
    for (int i = 0; i < 10; ++i) a[i] = 0.f;

    for (int e = gs + q; e < ge; e += 4) {
        unsigned s = csr[e];
        uint4 rA = zl4[(size_t)s * 2];
        uint4 rB = zl4[(size_t)s * 2 + 1];
        a[0] += bflo(rA.x); a[1] += bfhi(rA.x);
        a[2] += bflo(rA.y); a[3] += bfhi(rA.y);
        a[4] += bflo(rA.z);
        a[5] += bflo(rB.x); a[6] += bfhi(rB.x);
        a[7] += bflo(rB.y); a[8] += bfhi(rB.y);
        a[9] += bflo(rB.z);
    }
    #pragma unroll
    for (int i = 0; i < 10; ++i) {
        a[i] += __shfl_xor(a[i], 1);
        a[i] += __shfl_xor(a[i], 2);
    }

    if (q != 0 || node >= N) return;
    const float* zr = zrb + (size_t)node * 12;
    const float inv = zr[10];
    float v[10];
    float mx = -1e30f;
    #pragma unroll
    for (int k = 0; k < 10; ++k) {
        v[k] = a[k] * inv + zr[k];
        mx = fmaxf(mx, v[k]);
    }
    float ssum = 0.f;
    #pragma unroll
    for (int k = 0; k < 10; ++k) ssum += expf(v[k] - mx);
    const float lse = mx + logf(ssum);
    float2* o = reinterpret_cast<float2*>(out + (size_t)node * 10);
    o[0] = make_float2(v[0] - lse, v[1] - lse);
    o[1] = make_float2(v[2] - lse, v[3] - lse);
    o[2] = make_float2(v[4] - lse, v[5] - lse);
    o[3] = make_float2(v[6] - lse, v[7] - lse);
    o[4] = make_float2(v[8] - lse, v[9] - lse);
}

extern "C" void kernel_launch(void* const* d_in, const int* in_sizes, int n_in,
                              void* d_out, int out_size, void* d_ws, size_t ws_size,
                              hipStream_t stream) {
    const float* x   = (const float*)d_in[0];
    const int*   ei  = (const int*)d_in[1];
    const float* W1l = (const float*)d_in[2];
    const float* b1l = (const float*)d_in[3];
    const float* W1r = (const float*)d_in[4];
    const float* W2l = (const float*)d_in[5];
    const float* b2l = (const float*)d_in[6];
    const float* W2r = (const float*)d_in[7];
    float* out = (float*)d_out;

    const int N = in_sizes[0] / 500;
    const int E = in_sizes[1] / 2;
    const int B = (N + BSZ - 1) >> BSH;       // buckets of BSZ nodes
    const int chunk = (E + P_BLOCKS - 1) / P_BLOCKS;

    // workspace: ints first, then 16B-aligned arrays (~33 MB)
    int* hist_g  = (int*)d_ws;                       // [B*P_BLOCKS] (hist, then base in-place)
    int* tot     = hist_g + (size_t)B * P_BLOCKS;    // [B]
    int* bstart  = tot + B;                          // [B+1]
    int* nodeoff = bstart + (B + 1);                 // [B*64+1]
    unsigned* csr = (unsigned*)(nodeoff + (size_t)B * BSZ + 1); // [E]
    size_t off = ((char*)(csr + E) - (char*)d_ws + 15) & ~(size_t)15;
    unsigned short* yab = (unsigned short*)((char*)d_ws + off);  // [N,8] bf16
    off = (off + (size_t)N * 16 + 15) & ~(size_t)15;
    unsigned short* zlb = (unsigned short*)((char*)d_ws + off);  // [N,16] bf16
    off = (off + (size_t)N * 32 + 15) & ~(size_t)15;
    float* yr  = (float*)((char*)d_ws + off);                    // [N,8] f32
    float* zrb = yr + (size_t)8 * N;                             // [N,12] f32

    proj1_kernel<<<1024, 256, 0, stream>>>(x, W1l, W1r, yab, yr, N);
    hist_kernel<<<P_BLOCKS, 512, 0, stream>>>(ei, E, chunk, B, hist_g);
    bsum_kernel<<<B, 256, 0, stream>>>(hist_g, tot);
    base_kernel<<<B, 256, 0, stream>>>(hist_g, tot, B, bstart);
    scatter2_kernel<<<P_BLOCKS, 512, 0, stream>>>(ei, E, chunk, B, hist_g, csr);
    sortB_kernel<<<B, 256, 0, stream>>>(bstart, csr, nodeoff, B);
    agg1R_kernel<<<B, 256, 0, stream>>>(nodeoff, csr, yab, yr, b1l, W2l, b2l, W2r,
                                        zlb, zrb, N);
    agg2R_kernel<<<B, 256, 0, stream>>>(nodeoff, csr, zlb, zrb, out, N);
}